// Round 5
// baseline (6604.863 us; speedup 1.0000x reference)
//
#include <hip/hip_runtime.h>
#include <math.h>

#define DIM      1024
#define K_GATES  24
#define NMAX     512          // max Chebyshev terms per gate
#define QUAD_M   2048         // quadrature points for Bessel J_n
#define BBOUND   66.0f        // spectral bound: GUE radius 64 + margin
#define ROWS     16           // rows per block
#define NBLOCKS  64           // 64 * 16 = 1024 rows
#define NTHREADS 1024         // 16 waves of 64

// ---------------- self-tagged 8B words: {low32 = f32 bits, high32 = epoch}
// Single-word atomicity replaces ALL cross-address ordering: the tag and the
// value travel in one naturally-aligned 64-bit agent-scope access, so no
// fence / flag / store-visibility-order assumption is needed.
__device__ __forceinline__ void tagStore(unsigned long long* p, float v, unsigned e) {
    unsigned long long w = ((unsigned long long)e << 32) | (unsigned long long)__float_as_uint(v);
    __hip_atomic_store(p, w, __ATOMIC_RELAXED, __HIP_MEMORY_SCOPE_AGENT);
}

// ---------------------------------------------------------------- init state
// psi = pad(feature, 1024)/||feature||, published into parity 0 with epoch 0
__global__ __launch_bounds__(1024) void init_state(const float* __restrict__ f,
                                                   int nfeat,
                                                   unsigned long long* __restrict__ wre,
                                                   unsigned long long* __restrict__ wim) {
    __shared__ float red[16];
    __shared__ float invn_s;
    int t = threadIdx.x;
    float v = (t < nfeat) ? f[t] : 0.f;
    float s = v * v;
    #pragma unroll
    for (int o = 1; o < 64; o <<= 1) s += __shfl_xor(s, o);
    if ((t & 63) == 0) red[t >> 6] = s;
    __syncthreads();
    if (t == 0) {
        float tot = 0.f;
        for (int i = 0; i < 16; i++) tot += red[i];
        invn_s = 1.0f / sqrtf(tot);
    }
    __syncthreads();
    tagStore(&wre[t], v * invn_s, 0u);   // parity 0, epoch 0
    tagStore(&wim[t], 0.f, 0u);
}

// ---------------------------------------------------------------- Bessel coefs
// c_n(k) = (n==0?1:2) * (-i)^n * J_n(tau_k),  tau_k = theta_k * BBOUND
__global__ __launch_bounds__(256) void bessel_coef(const float* __restrict__ theta,
                                                   float2* __restrict__ coefs) {
    int n = blockIdx.x;   // 0..NMAX-1
    int k = blockIdx.y;   // 0..K_GATES-1
    double tau = (double)theta[k] * (double)BBOUND;
    int t = threadIdx.x;  // 256
    double acc = 0.0;
    #pragma unroll
    for (int i = 0; i < QUAD_M / 256; i++) {
        int j = t + 256 * i;
        double phi = (2.0 * M_PI / (double)QUAD_M) * (double)j;
        acc += cos((double)n * phi - tau * sin(phi));
    }
    #pragma unroll
    for (int o = 1; o < 64; o <<= 1) acc += __shfl_xor(acc, o);
    __shared__ double red[4];
    if ((t & 63) == 0) red[t >> 6] = acc;
    __syncthreads();
    if (t == 0) {
        double J = (red[0] + red[1] + red[2] + red[3]) / (double)QUAD_M;
        double f = (n == 0) ? 1.0 : 2.0;
        float cr = 0.f, cim = 0.f;
        switch (n & 3) {                 // (-i)^n
            case 0: cr  =  (float)(f * J); break;
            case 1: cim = -(float)(f * J); break;
            case 2: cr  = -(float)(f * J); break;
            case 3: cim =  (float)(f * J); break;
        }
        coefs[k * NMAX + n] = make_float2(cr, cim);
    }
}

// ---------------------------------------------------------------- truncation
__global__ __launch_bounds__(NMAX) void trunc_len(const float2* __restrict__ coefs,
                                                  int* __restrict__ nterm) {
    int k = blockIdx.x;
    int t = threadIdx.x;  // 512
    float2 c = coefs[k * NMAX + t];
    float mag = fabsf(c.x) + fabsf(c.y);
    int myn = (mag > 5e-7f) ? t : 0;   // round-2-validated cutoff (absmax 3.8e-6)
    #pragma unroll
    for (int o = 1; o < 64; o <<= 1) myn = max(myn, __shfl_xor(myn, o));
    __shared__ int red[8];
    if ((t & 63) == 0) red[t >> 6] = myn;
    __syncthreads();
    if (t == 0) {
        int m = 1;
        for (int i = 0; i < 8; i++) m = max(m, red[i]);
        nterm[k] = min(m, NMAX - 1);
    }
}

// ---------------------------------------------------------------- main kernel
__global__ __launch_bounds__(NTHREADS) void evolve(const float* __restrict__ gre,
                                                   const float* __restrict__ gim,
                                                   unsigned long long* __restrict__ wre, // [2][DIM]
                                                   unsigned long long* __restrict__ wim, // [2][DIM]
                                                   const float2* __restrict__ coefs,
                                                   const int* __restrict__ nterm,
                                                   float* __restrict__ out) {
    __shared__ float2 Gs[ROWS * DIM];        // 128 KiB: this block's 16 rows of Gtilde
    __shared__ float2 xs[DIM];               // 8 KiB: staged Chebyshev vector
    const int t = threadIdx.x, b = blockIdx.x;
    const int wave = t >> 6, lane = t & 63;
    const int r0 = b * ROWS;
    const int r = r0 + wave;                 // this wave's row (global component idx)
    const float hB = 0.5f / BBOUND;

    unsigned e = 0;                          // current consume-epoch; parity = e&1
    float2 acc = make_float2(0.f, 0.f);

    // fetch(e): spin until BOTH tagged words of element t show epoch e, stage to LDS.
    // publish(e+1): store this wave's row tagged e+1 into parity (e+1)&1.
    // Safety chain (no fences needed): publish(e+1) <= fetch(e) barrier <= all
    // blocks publish(e) <= each block's fetch(e-1) loads complete.  Tag+value
    // share one 8B word -> no cross-address visibility ordering assumed.

    for (int k = 0; k < K_GATES; k++) {
        const float* R = gre + (size_t)k * DIM * DIM;
        const float* I = gim + (size_t)k * DIM * DIM;

        // ---- stage Gtilde = ((R+R^T)/2 + i (I-I^T)/2)/B into LDS ----
        // pass A: column panel R[:, r0:r0+16], I[:, r0:r0+16] (64 B per row)
        {
            const float4* Rc = (const float4*)(R + (size_t)t * DIM + r0);
            const float4* Ic = (const float4*)(I + (size_t)t * DIM + r0);
            float4 ra0 = Rc[0], ra1 = Rc[1], ra2 = Rc[2], ra3 = Rc[3];
            float4 ia0 = Ic[0], ia1 = Ic[1], ia2 = Ic[2], ia3 = Ic[3];
            Gs[ 0 * DIM + t] = make_float2(hB * ra0.x, -hB * ia0.x);
            Gs[ 1 * DIM + t] = make_float2(hB * ra0.y, -hB * ia0.y);
            Gs[ 2 * DIM + t] = make_float2(hB * ra0.z, -hB * ia0.z);
            Gs[ 3 * DIM + t] = make_float2(hB * ra0.w, -hB * ia0.w);
            Gs[ 4 * DIM + t] = make_float2(hB * ra1.x, -hB * ia1.x);
            Gs[ 5 * DIM + t] = make_float2(hB * ra1.y, -hB * ia1.y);
            Gs[ 6 * DIM + t] = make_float2(hB * ra1.z, -hB * ia1.z);
            Gs[ 7 * DIM + t] = make_float2(hB * ra1.w, -hB * ia1.w);
            Gs[ 8 * DIM + t] = make_float2(hB * ra2.x, -hB * ia2.x);
            Gs[ 9 * DIM + t] = make_float2(hB * ra2.y, -hB * ia2.y);
            Gs[10 * DIM + t] = make_float2(hB * ra2.z, -hB * ia2.z);
            Gs[11 * DIM + t] = make_float2(hB * ra2.w, -hB * ia2.w);
            Gs[12 * DIM + t] = make_float2(hB * ra3.x, -hB * ia3.x);
            Gs[13 * DIM + t] = make_float2(hB * ra3.y, -hB * ia3.y);
            Gs[14 * DIM + t] = make_float2(hB * ra3.z, -hB * ia3.z);
            Gs[15 * DIM + t] = make_float2(hB * ra3.w, -hB * ia3.w);
        }
        __syncthreads();
        // pass B: row panel (coalesced), accumulate into LDS
        {
            const float4* Rr = (const float4*)(R + (size_t)r * DIM);
            const float4* Ir = (const float4*)(I + (size_t)r * DIM);
            float4* G4 = (float4*)(Gs + (size_t)wave * DIM);
            #pragma unroll
            for (int m = 0; m < 4; m++) {
                int i4 = lane + 64 * m;          // 256 float4 = 1024 floats
                float4 rv = Rr[i4], iv = Ir[i4];
                float4 g0 = G4[2 * i4], g1 = G4[2 * i4 + 1];
                g0.x += hB * rv.x; g0.y += hB * iv.x;
                g0.z += hB * rv.y; g0.w += hB * iv.y;
                g1.x += hB * rv.z; g1.y += hB * iv.z;
                g1.z += hB * rv.w; g1.w += hB * iv.w;
                G4[2 * i4] = g0; G4[2 * i4 + 1] = g1;
            }
        }
        __syncthreads();

        const int N = nterm[k];
        const float2* C = coefs + (size_t)k * NMAX;

        float2 t_prev, t_cur;
        bool first = true;

        for (int n = 1; n <= N; n++) {
            // ---- fetch(e): spin on self-tagged words, stage x into LDS ----
            {
                const unsigned long long* pre = wre + (size_t)(e & 1) * DIM + t;
                const unsigned long long* pim = wim + (size_t)(e & 1) * DIM + t;
                unsigned long long a, bw;
                for (;;) {
                    a  = __hip_atomic_load(pre, __ATOMIC_RELAXED, __HIP_MEMORY_SCOPE_AGENT);
                    bw = __hip_atomic_load(pim, __ATOMIC_RELAXED, __HIP_MEMORY_SCOPE_AGENT);
                    if (((unsigned)(a >> 32) == e) & ((unsigned)(bw >> 32) == e)) break;
                    __builtin_amdgcn_s_sleep(1);
                }
                xs[t] = make_float2(__uint_as_float((unsigned)a),
                                    __uint_as_float((unsigned)bw));
            }
            __syncthreads();

            // w = Gtilde_row . x  (complex dot over 1024, one wave per row)
            float sre = 0.f, sim = 0.f;
            {
                const float4* x4 = (const float4*)xs;
                const float4* g4 = (const float4*)(Gs + (size_t)wave * DIM);
                #pragma unroll
                for (int m = 0; m < 8; m++) {
                    int idx = lane + 64 * m;     // 512 float4 = 1024 complex
                    float4 xv = x4[idx];
                    float4 gv = g4[idx];
                    sre += gv.x * xv.x - gv.y * xv.y + gv.z * xv.z - gv.w * xv.w;
                    sim += gv.x * xv.y + gv.y * xv.x + gv.z * xv.w + gv.w * xv.z;
                }
                #pragma unroll
                for (int o = 1; o < 64; o <<= 1) {
                    sre += __shfl_xor(sre, o);
                    sim += __shfl_xor(sim, o);
                }
            }
            float2 w = make_float2(sre, sim);

            float2 t_next;
            if (first) {
                t_prev = xs[r];                  // T_0 = psi
                t_next = w;                      // T_1 = Gt psi
                float2 c0 = C[0], c1 = C[1];
                acc.x = c0.x * t_prev.x - c0.y * t_prev.y + c1.x * w.x - c1.y * w.y;
                acc.y = c0.x * t_prev.y + c0.y * t_prev.x + c1.x * w.y + c1.y * w.x;
                first = false;
            } else {
                t_next = make_float2(2.f * w.x - t_prev.x, 2.f * w.y - t_prev.y);
                float2 cn = C[n];
                acc.x += cn.x * t_next.x - cn.y * t_next.y;
                acc.y += cn.x * t_next.y + cn.y * t_next.x;
                t_prev = t_cur;
            }
            t_cur = t_next;

            // ---- publish(e+1): t_N is consumed by no one -> publish acc there
            {
                float2 val = (n == N) ? acc : t_next;
                unsigned ne = e + 1;
                if (lane == 0) {
                    tagStore(wre + (size_t)(ne & 1) * DIM + r, val.x, ne);
                    tagStore(wim + (size_t)(ne & 1) * DIM + r, val.y, ne);
                }
            }
            __syncthreads();   // xs WAR: all waves done reading xs before next fetch
            e++;
        }
    }

    // probs = |psi|^2 (acc holds this wave's row of the final state)
    if (lane == 0) out[r] = acc.x * acc.x + acc.y * acc.y;
}

// ---------------------------------------------------------------- launch
extern "C" void kernel_launch(void* const* d_in, const int* in_sizes, int n_in,
                              void* d_out, int out_size, void* d_ws, size_t ws_size,
                              hipStream_t stream) {
    const float* feat  = (const float*)d_in[0];   // 1000
    const float* theta = (const float*)d_in[1];   // 24
    const float* gre   = (const float*)d_in[2];   // 24*1024*1024
    const float* gim   = (const float*)d_in[3];

    // ws: wre[2][1024] u64 | wim[2][1024] u64 | coefs[24][512] float2 | nterm[24]
    char* base = (char*)d_ws;
    unsigned long long* wre   = (unsigned long long*)base;
    unsigned long long* wim   = (unsigned long long*)(base + 2 * DIM * 8);
    float2*             coefs = (float2*)(base + 4 * DIM * 8);
    int*                nterm = (int*)(base + 4 * DIM * 8 + K_GATES * NMAX * sizeof(float2));
    float* outp = (float*)d_out;

    init_state<<<1, 1024, 0, stream>>>(feat, in_sizes[0], wre, wim);
    bessel_coef<<<dim3(NMAX, K_GATES), 256, 0, stream>>>(theta, coefs);
    trunc_len<<<K_GATES, NMAX, 0, stream>>>(coefs, nterm);

    void* args[] = {(void*)&gre, (void*)&gim, (void*)&wre, (void*)&wim,
                    (void*)&coefs, (void*)&nterm, (void*)&outp};
    hipLaunchCooperativeKernel((void*)evolve, dim3(NBLOCKS), dim3(NTHREADS),
                               args, 0, stream);
}

// Round 7
// 6603.739 us; speedup vs baseline: 1.0002x; 1.0002x over previous
//
#include <hip/hip_runtime.h>
#include <math.h>

#define DIM      1024
#define K_GATES  24
#define NMAX     512          // max Chebyshev terms per gate
#define QUAD_M   2048         // quadrature points for Bessel J_n
#define BBOUND   66.0f        // spectral bound: GUE radius 64 + margin
#define ROWS     16           // rows per block (1 row per wave; row held in VGPRs)
#define NBLOCKS  64           // 64 * 16 = 1024 rows
#define NTHREADS 1024         // 16 waves of 64

// ---------------- self-tagged 8B words: {low32 = f32 bits, high32 = epoch}
// Tag+value travel in one naturally-aligned 64-bit agent-scope access.
// PROTOCOL IS VALIDATED (R5 passed all replays): two __syncthreads per step,
// spin on tag equality. Do NOT weaken (R3/R4/R6 all raced intermittently).
__device__ __forceinline__ void tagStore(unsigned long long* p, float v, unsigned e) {
    unsigned long long w = ((unsigned long long)e << 32) | (unsigned long long)__float_as_uint(v);
    __hip_atomic_store(p, w, __ATOMIC_RELAXED, __HIP_MEMORY_SCOPE_AGENT);
}

// ---------------------------------------------------------------- init state
__global__ __launch_bounds__(1024) void init_state(const float* __restrict__ f,
                                                   int nfeat,
                                                   unsigned long long* __restrict__ wre,
                                                   unsigned long long* __restrict__ wim) {
    __shared__ float red[16];
    __shared__ float invn_s;
    int t = threadIdx.x;
    float v = (t < nfeat) ? f[t] : 0.f;
    float s = v * v;
    #pragma unroll
    for (int o = 1; o < 64; o <<= 1) s += __shfl_xor(s, o);
    if ((t & 63) == 0) red[t >> 6] = s;
    __syncthreads();
    if (t == 0) {
        float tot = 0.f;
        for (int i = 0; i < 16; i++) tot += red[i];
        invn_s = 1.0f / sqrtf(tot);
    }
    __syncthreads();
    tagStore(&wre[t], v * invn_s, 0u);   // parity 0, epoch 0
    tagStore(&wim[t], 0.f, 0u);
}

// ---------------------------------------------------------------- Bessel coefs
// c_n(k) = (n==0?1:2) * (-i)^n * J_n(tau_k),  tau_k = theta_k * BBOUND
__global__ __launch_bounds__(256) void bessel_coef(const float* __restrict__ theta,
                                                   float2* __restrict__ coefs) {
    int n = blockIdx.x;
    int k = blockIdx.y;
    double tau = (double)theta[k] * (double)BBOUND;
    int t = threadIdx.x;
    double acc = 0.0;
    #pragma unroll
    for (int i = 0; i < QUAD_M / 256; i++) {
        int j = t + 256 * i;
        double phi = (2.0 * M_PI / (double)QUAD_M) * (double)j;
        acc += cos((double)n * phi - tau * sin(phi));
    }
    #pragma unroll
    for (int o = 1; o < 64; o <<= 1) acc += __shfl_xor(acc, o);
    __shared__ double red[4];
    if ((t & 63) == 0) red[t >> 6] = acc;
    __syncthreads();
    if (t == 0) {
        double J = (red[0] + red[1] + red[2] + red[3]) / (double)QUAD_M;
        double f = (n == 0) ? 1.0 : 2.0;
        float cr = 0.f, cim = 0.f;
        switch (n & 3) {                 // (-i)^n
            case 0: cr  =  (float)(f * J); break;
            case 1: cim = -(float)(f * J); break;
            case 2: cr  = -(float)(f * J); break;
            case 3: cim =  (float)(f * J); break;
        }
        coefs[k * NMAX + n] = make_float2(cr, cim);
    }
}

// ---------------------------------------------------------------- truncation
__global__ __launch_bounds__(NMAX) void trunc_len(const float2* __restrict__ coefs,
                                                  int* __restrict__ nterm) {
    int k = blockIdx.x;
    int t = threadIdx.x;
    float2 c = coefs[k * NMAX + t];
    float mag = fabsf(c.x) + fabsf(c.y);
    int myn = (mag > 2e-6f) ? t : 0;   // 36x margin at 5e-7 (R5) -> modestly looser
    #pragma unroll
    for (int o = 1; o < 64; o <<= 1) myn = max(myn, __shfl_xor(myn, o));
    __shared__ int red[8];
    if ((t & 63) == 0) red[t >> 6] = myn;
    __syncthreads();
    if (t == 0) {
        int m = 1;
        for (int i = 0; i < 8; i++) m = max(m, red[i]);
        nterm[k] = min(m, NMAX - 1);
    }
}

// ---------------------------------------------------------------- main kernel
__global__ __launch_bounds__(NTHREADS) void evolve(const float* __restrict__ gre,
                                                   const float* __restrict__ gim,
                                                   unsigned long long* __restrict__ wre, // [2][DIM]
                                                   unsigned long long* __restrict__ wim, // [2][DIM]
                                                   const float2* __restrict__ coefs,
                                                   const int* __restrict__ nterm,
                                                   float* __restrict__ out) {
    __shared__ float2 Gstage[ROWS][DIM];     // 128 KiB: per-gate transpose staging only
    __shared__ float2 xs[DIM];               // 8 KiB: staged Chebyshev vector
    const int t = threadIdx.x, b = blockIdx.x;
    const int wave = t >> 6, lane = t & 63;
    const int r0 = b * ROWS;
    const int r = r0 + wave;                 // this wave's row
    const float hB = 0.5f / BBOUND;

    unsigned e = 0;                          // consume-epoch; parity = e&1
    float2 acc = make_float2(0.f, 0.f);
    float4 greg[8];                          // G-row in VGPRs: 16 complex / lane

    for (int k = 0; k < K_GATES; k++) {
        const float* R = gre + (size_t)k * DIM * DIM;
        const float* I = gim + (size_t)k * DIM * DIM;

        // ---- stage transpose part: Gstage[j][t] = (hB R[t][r0+j], -hB I[t][r0+j])
        {
            const float4* Rc = (const float4*)(R + (size_t)t * DIM + r0);
            const float4* Ic = (const float4*)(I + (size_t)t * DIM + r0);
            float4 ra0 = Rc[0], ra1 = Rc[1], ra2 = Rc[2], ra3 = Rc[3];
            float4 ia0 = Ic[0], ia1 = Ic[1], ia2 = Ic[2], ia3 = Ic[3];
            Gstage[ 0][t] = make_float2(hB * ra0.x, -hB * ia0.x);
            Gstage[ 1][t] = make_float2(hB * ra0.y, -hB * ia0.y);
            Gstage[ 2][t] = make_float2(hB * ra0.z, -hB * ia0.z);
            Gstage[ 3][t] = make_float2(hB * ra0.w, -hB * ia0.w);
            Gstage[ 4][t] = make_float2(hB * ra1.x, -hB * ia1.x);
            Gstage[ 5][t] = make_float2(hB * ra1.y, -hB * ia1.y);
            Gstage[ 6][t] = make_float2(hB * ra1.z, -hB * ia1.z);
            Gstage[ 7][t] = make_float2(hB * ra1.w, -hB * ia1.w);
            Gstage[ 8][t] = make_float2(hB * ra2.x, -hB * ia2.x);
            Gstage[ 9][t] = make_float2(hB * ra2.y, -hB * ia2.y);
            Gstage[10][t] = make_float2(hB * ra2.z, -hB * ia2.z);
            Gstage[11][t] = make_float2(hB * ra2.w, -hB * ia2.w);
            Gstage[12][t] = make_float2(hB * ra3.x, -hB * ia3.x);
            Gstage[13][t] = make_float2(hB * ra3.y, -hB * ia3.y);
            Gstage[14][t] = make_float2(hB * ra3.z, -hB * ia3.z);
            Gstage[15][t] = make_float2(hB * ra3.w, -hB * ia3.w);
        }
        __syncthreads();
        // ---- combine with coalesced row part -> G-row in VGPRs
        {
            const float2* Rr = (const float2*)(R + (size_t)r * DIM);
            const float2* Ir = (const float2*)(I + (size_t)r * DIM);
            const float4* Gt = (const float4*)Gstage[wave];
            #pragma unroll
            for (int m = 0; m < 8; m++) {
                int idx = lane + 64 * m;
                float4 gt = Gt[idx];                 // transpose part (2 complex)
                float2 rv = Rr[idx], iv = Ir[idx];   // row part
                greg[m] = make_float4(gt.x + hB * rv.x, gt.y + hB * iv.x,
                                      gt.z + hB * rv.y, gt.w + hB * iv.y);
            }
        }
        __syncthreads();   // Gstage free for next gate's staging

        const int N = nterm[k];
        const float2* C = coefs + (size_t)k * NMAX;

        float2 t_prev, t_cur;
        bool first = true;

        for (int n = 1; n <= N; n++) {
            const int p = e & 1;
            // ---- fetch(e): spin on self-tagged words, stage x into LDS ----
            {
                const unsigned long long* pre = wre + (size_t)p * DIM + t;
                const unsigned long long* pim = wim + (size_t)p * DIM + t;
                unsigned long long a, bw;
                for (;;) {
                    a  = __hip_atomic_load(pre, __ATOMIC_RELAXED, __HIP_MEMORY_SCOPE_AGENT);
                    bw = __hip_atomic_load(pim, __ATOMIC_RELAXED, __HIP_MEMORY_SCOPE_AGENT);
                    if (((unsigned)(a >> 32) == e) & ((unsigned)(bw >> 32) == e)) break;
                    __builtin_amdgcn_s_sleep(1);
                }
                xs[t] = make_float2(__uint_as_float((unsigned)a),
                                    __uint_as_float((unsigned)bw));
            }
            __syncthreads();                 // barrier 1 (validated protocol)

            // w = G_row . x  (G from VGPRs, x from LDS)
            float sre = 0.f, sim = 0.f;
            {
                const float4* x4 = (const float4*)xs;
                #pragma unroll
                for (int m = 0; m < 8; m++) {
                    float4 xv = x4[lane + 64 * m];
                    float4 gv = greg[m];
                    sre += gv.x * xv.x - gv.y * xv.y + gv.z * xv.z - gv.w * xv.w;
                    sim += gv.x * xv.y + gv.y * xv.x + gv.z * xv.w + gv.w * xv.z;
                }
                #pragma unroll
                for (int o = 1; o < 64; o <<= 1) {
                    sre += __shfl_xor(sre, o);
                    sim += __shfl_xor(sim, o);
                }
            }
            float2 w = make_float2(sre, sim);

            float2 t_next;
            if (first) {
                t_prev = xs[r];                  // T_0 = psi
                t_next = w;                      // T_1 = Gt psi
                float2 c0 = C[0], c1 = C[1];
                acc.x = c0.x * t_prev.x - c0.y * t_prev.y + c1.x * w.x - c1.y * w.y;
                acc.y = c0.x * t_prev.y + c0.y * t_prev.x + c1.x * w.y + c1.y * w.x;
                first = false;
            } else {
                t_next = make_float2(2.f * w.x - t_prev.x, 2.f * w.y - t_prev.y);
                float2 cn = C[n];
                acc.x += cn.x * t_next.x - cn.y * t_next.y;
                acc.y += cn.x * t_next.y + cn.y * t_next.x;
                t_prev = t_cur;
            }
            t_cur = t_next;

            // ---- publish(e+1); t_N unused by anyone -> publish gate result acc
            {
                float2 val = (n == N) ? acc : t_next;
                unsigned ne = e + 1;
                if (lane == 0) {
                    tagStore(wre + (size_t)(ne & 1) * DIM + r, val.x, ne);
                    tagStore(wim + (size_t)(ne & 1) * DIM + r, val.y, ne);
                }
            }
            __syncthreads();                 // barrier 2 (validated protocol — keep!)
            e++;
        }
    }

    // probs = |psi|^2 (acc holds this wave's row of the final state)
    if (lane == 0) out[r] = acc.x * acc.x + acc.y * acc.y;
}

// ---------------------------------------------------------------- launch
extern "C" void kernel_launch(void* const* d_in, const int* in_sizes, int n_in,
                              void* d_out, int out_size, void* d_ws, size_t ws_size,
                              hipStream_t stream) {
    const float* feat  = (const float*)d_in[0];   // 1000
    const float* theta = (const float*)d_in[1];   // 24
    const float* gre   = (const float*)d_in[2];   // 24*1024*1024
    const float* gim   = (const float*)d_in[3];

    // ws: wre[2][1024] u64 | wim[2][1024] u64 | coefs[24][512] float2 | nterm[24]
    char* base = (char*)d_ws;
    unsigned long long* wre   = (unsigned long long*)base;
    unsigned long long* wim   = (unsigned long long*)(base + 2 * DIM * 8);
    float2*             coefs = (float2*)(base + 4 * DIM * 8);
    int*                nterm = (int*)(base + 4 * DIM * 8 + K_GATES * NMAX * sizeof(float2));
    float* outp = (float*)d_out;

    init_state<<<1, 1024, 0, stream>>>(feat, in_sizes[0], wre, wim);
    bessel_coef<<<dim3(NMAX, K_GATES), 256, 0, stream>>>(theta, coefs);
    trunc_len<<<K_GATES, NMAX, 0, stream>>>(coefs, nterm);

    void* args[] = {(void*)&gre, (void*)&gim, (void*)&wre, (void*)&wim,
                    (void*)&coefs, (void*)&nterm, (void*)&outp};
    hipLaunchCooperativeKernel((void*)evolve, dim3(NBLOCKS), dim3(NTHREADS),
                               args, 0, stream);
}